// Round 10
// baseline (858.115 us; speedup 1.0000x reference)
//
#include <hip/hip_runtime.h>
#include <hip/hip_bf16.h>
#include <math.h>

#define N_   8192
#define P_   64
#define C_   128
#define M_   4096
#define MW_  (M_ * P_)     // 262144
#define A_   131072
#define BL_  65536
#define NROWS_ (N_ * P_)   // 524288

typedef __attribute__((ext_vector_type(8))) __bf16 bf16x8;
typedef __attribute__((ext_vector_type(4))) float f32x4;
typedef __attribute__((ext_vector_type(2))) __bf16 bf16x2;

__device__ __forceinline__ float wave_sum(float v) {
#pragma unroll
  for (int o = 32; o > 0; o >>= 1) v += __shfl_xor(v, o, 64);
  return v;
}

// ---------------- flags ----------------
__global__ __launch_bounds__(256) void k_set8(unsigned char* p, int n) {
  int i = blockIdx.x * 256 + threadIdx.x;
  if (i < n) p[i] = 0;
}
__global__ __launch_bounds__(256) void k_scatter2(unsigned char* p,
                                                  const int* __restrict__ ia,
                                                  const int* __restrict__ ib) {
  int i = blockIdx.x * 256 + threadIdx.x;
  if (i < A_) p[ia[i]] = 1;
  else {
    int j = i - A_;
    if (j < BL_) p[ib[j]] = 2;
  }
}

// ---------------- weight prep: all bf16 transposed copies in one launch ----------------
__global__ __launch_bounds__(256) void k_prep(const float* __restrict__ qkvw,
                                              const float* __restrict__ projw,
                                              const float* __restrict__ w1,
                                              const float* __restrict__ w2,
                                              __bf16* __restrict__ qkvt,
                                              __bf16* __restrict__ projt,
                                              __bf16* __restrict__ w1t,
                                              __bf16* __restrict__ w2t) {
  int i = blockIdx.x * 256 + threadIdx.x;
  if (i < 384 * 128) {
    int col = i >> 7, row = i & 127;
    qkvt[i] = (__bf16)qkvw[row * 384 + col];
  } else if (i < 384 * 128 + 128 * 128) {
    int j = i - 384 * 128;
    int col = j >> 7, row = j & 127;
    projt[j] = (__bf16)projw[row * 128 + col];
  } else if (i < 384 * 128 + 128 * 128 + 512 * 128) {
    int j = i - 384 * 128 - 128 * 128;
    int col = j >> 7, row = j & 127;
    w1t[j] = (__bf16)w1[row * 512 + col];
  } else {
    int j = i - 384 * 128 - 128 * 128 - 512 * 128;
    int col = j >> 9, row = j & 511;
    w2t[j] = (__bf16)w2[row * 128 + col];
  }
}

// ---------------- LN1 over all rows -> out (float4, 1 row per half-wave) ----------------
__global__ __launch_bounds__(256) void k_ln_all(const float* __restrict__ x,
                                                const float* __restrict__ w,
                                                const float* __restrict__ b,
                                                float* __restrict__ out) {
  int hw = threadIdx.x >> 5, l = threadIdx.x & 31;
  size_t row = (size_t)blockIdx.x * 8 + hw;
  float4 v = ((const float4*)(x + row * 128))[l];
  float s = (v.x + v.y) + (v.z + v.w);
#pragma unroll
  for (int o = 1; o < 32; o <<= 1) s += __shfl_xor(s, o, 64);
  float mean = s * (1.0f / 128.0f);
  float d0 = v.x - mean, d1 = v.y - mean, d2 = v.z - mean, d3 = v.w - mean;
  float q = (d0 * d0 + d1 * d1) + (d2 * d2 + d3 * d3);
#pragma unroll
  for (int o = 1; o < 32; o <<= 1) q += __shfl_xor(q, o, 64);
  float inv = rsqrtf(q * (1.0f / 128.0f) + 1e-6f);
  float4 wv = ((const float4*)w)[l];
  float4 bv = ((const float4*)b)[l];
  float4 o4;
  o4.x = d0 * inv * wv.x + bv.x;
  o4.y = d1 * inv * wv.y + bv.y;
  o4.z = d2 * inv * wv.z + bv.z;
  o4.w = d3 * inv * wv.w + bv.w;
  ((float4*)(out + row * 128))[l] = o4;
}

// ---------------- attention: one block per partition, 8 waves (2 per head) ----------------
// LDS (3 blocks/CU by LDS; 2 by VGPR): XV 64x132 bf16 (16896B; Xs -> Vt[4][32][66])
//  + scratch 4x4352 per HEAD (Q[64][34]+K[64][34]; Ps[64][68]; Os[64][36] overlays)
//  + srow/fl/sm2/si2 832B => 52544B.
// Wave pair (mh=0/1) splits the 64 Q-rows of head h; per-wave serial chains halve.
// R5 lesson: (512,6) VGPR cap=85 collapsed the allocator (VGPR 40 + spills).
// Loose cap (512,4) => 128 VGPR; kernel needs ~90-110 => no spills, 16 waves/CU.
// Phase 4 keeps R9's y-fusion (fl==1 rows get y = xa + g1*o directly).
__global__ __launch_bounds__(512, 4) void k_attn(
    const int* __restrict__ iw,
    const int* __restrict__ ip, const unsigned char* __restrict__ flags,
    const float* __restrict__ ln1w, const float* __restrict__ ln1b,
    const __bf16* __restrict__ qkvt, const float* __restrict__ qkvb,
    const __bf16* __restrict__ projt, const float* __restrict__ projb,
    const float* __restrict__ g1,
    float* out) {
  __shared__ __align__(16) __bf16 XV[64 * 132];
  __shared__ __align__(16) __bf16 scratch[4 * 4352];
  __shared__ int srow[64];
  __shared__ unsigned char fl[64];
  __shared__ float sm2[64];
  __shared__ float si2[64];

  const int tid = threadIdx.x;
  const int w = tid >> 6, lane = tid & 63;
  const int quad = lane >> 4, cl = lane & 15;
  const int h = w >> 1, mh = w & 1;
  const int m = blockIdx.x;

  // ---- resolve indices once ----
  if (tid < 64) {
    int s = ip[(m << 6) + tid];
    fl[tid] = flags[s];
    srow[tid] = iw[s >> 6] * 64 + (s & 63);
  }
  __syncthreads();

  __bf16* Xs = XV;  // [64][132] during phase 0 / af hoist
  const float lw0 = ln1w[2 * lane], lw1 = ln1w[2 * lane + 1];
  const float lb0 = ln1b[2 * lane], lb1 = ln1b[2 * lane + 1];

  // ---- phase 0: gather LN1 rows from out (8 rows/wave); re-LN asy, save stats ----
  {
    float2 xv[8];
#pragma unroll
    for (int ii = 0; ii < 8; ++ii) {
      int r = w * 8 + ii;
      xv[ii] = ((const float2*)(out + (size_t)srow[r] * 128))[lane];
    }
#pragma unroll
    for (int ii = 0; ii < 8; ++ii) {
      int r = w * 8 + ii;
      float y0 = xv[ii].x, y1 = xv[ii].y;
      if (fl[r] == 1) {
        float mean = wave_sum(y0 + y1) * (1.0f / 128.0f);
        float d0 = y0 - mean, d1 = y1 - mean;
        float inv = rsqrtf(wave_sum(d0 * d0 + d1 * d1) * (1.0f / 128.0f) + 1e-6f);
        if (lane == 0) { sm2[r] = mean; si2[r] = inv; }
        y0 = d0 * inv * lw0 + lb0;
        y1 = d1 * inv * lw1 + lb1;
      }
      bf16x2 p2;
      p2[0] = (__bf16)y0; p2[1] = (__bf16)y1;
      *(bf16x2*)&Xs[r * 132 + 2 * lane] = p2;
    }
  }
  __syncthreads();

  __bf16* wsc = scratch + h * 4352;   // per-HEAD region, shared by wave pair
  __bf16* Qs  = wsc;                  // [64][34]
  __bf16* Ks  = wsc + 2176;           // [64][34]
  __bf16* Vts = XV + h * 2112;        // [32][66] (Vt[d][pos]) -- overlays dead Xs
  __bf16* Ps  = wsc;                  // [64][68]  (overlays Q+K exactly)
  __bf16* Os  = wsc;                  // [64][36]  (overlays Ps after PV reads)

  // ---- af hoist: this wave's 32 rows (mt = mh*2+mtl) ----
  bf16x8 af[2][4];
#pragma unroll
  for (int mtl = 0; mtl < 2; ++mtl)
#pragma unroll
    for (int kt = 0; kt < 4; ++kt)
      af[mtl][kt] = *(const bf16x8*)&Xs[((mh * 2 + mtl) * 16 + cl) * 132 + kt * 32 + quad * 8];
  __syncthreads();  // Xs dead; Vt overlay may be written

  // ---- phase 1: QKV rows [32*mh, 32*mh+32) of head h ----
#pragma unroll
  for (int t = 0; t < 3; ++t) {
#pragma unroll
    for (int nt = 0; nt < 2; ++nt) {
      int col = h * 96 + t * 32 + nt * 16 + cl;
      bf16x8 bfr[4];
#pragma unroll
      for (int kt = 0; kt < 4; ++kt)
        bfr[kt] = *(const bf16x8*)&qkvt[(size_t)col * 128 + kt * 32 + quad * 8];
      float bias = qkvb[col];
      __builtin_amdgcn_s_setprio(1);
#pragma unroll
      for (int mtl = 0; mtl < 2; ++mtl) {
        int mt = mh * 2 + mtl;
        f32x4 acc = {bias, bias, bias, bias};
#pragma unroll
        for (int kt = 0; kt < 4; ++kt)
          acc = __builtin_amdgcn_mfma_f32_16x16x32_bf16(af[mtl][kt], bfr[kt], acc, 0, 0, 0);
        if (t == 0) {
#pragma unroll
          for (int r = 0; r < 4; ++r)
            Qs[(mt * 16 + quad * 4 + r) * 34 + nt * 16 + cl] = (__bf16)acc[r];
        } else if (t == 1) {
#pragma unroll
          for (int r = 0; r < 4; ++r)
            Ks[(mt * 16 + quad * 4 + r) * 34 + nt * 16 + cl] = (__bf16)acc[r];
        } else {
#pragma unroll
          for (int r = 0; r < 4; ++r)
            Vts[(nt * 16 + cl) * 66 + mt * 16 + quad * 4 + r] = (__bf16)acc[r];
        }
      }
      __builtin_amdgcn_s_setprio(0);
    }
  }
  __syncthreads();  // Q/K/Vt complete (cross-wave within pair)

  // ---- phase 2: S rows (this wave's 32) x all 64 cols ----
  f32x4 sc4[2][4];
  {
    bf16x8 bk[4];
#pragma unroll
    for (int nt = 0; nt < 4; ++nt)
      bk[nt] = *(const bf16x8*)&Ks[(nt * 16 + cl) * 34 + quad * 8];
    bf16x8 aq[2];
#pragma unroll
    for (int mtl = 0; mtl < 2; ++mtl)
      aq[mtl] = *(const bf16x8*)&Qs[((mh * 2 + mtl) * 16 + cl) * 34 + quad * 8];
    __builtin_amdgcn_s_setprio(1);
#pragma unroll
    for (int mtl = 0; mtl < 2; ++mtl)
#pragma unroll
      for (int nt = 0; nt < 4; ++nt) {
        f32x4 z = {0.f, 0.f, 0.f, 0.f};
        sc4[mtl][nt] = __builtin_amdgcn_mfma_f32_16x16x32_bf16(aq[mtl], bk[nt], z, 0, 0, 0);
      }
    __builtin_amdgcn_s_setprio(0);
  }
  __syncthreads();  // all Q/K reads done -> Ps may overlay Q/K

  const float scale = 0.17677669529663687f;  // 1/sqrt(32)
  bool blk[4];
#pragma unroll
  for (int nt = 0; nt < 4; ++nt) blk[nt] = (fl[nt * 16 + cl] == 2);
#pragma unroll
  for (int mtl = 0; mtl < 2; ++mtl)
#pragma unroll
    for (int nt = 0; nt < 4; ++nt)
#pragma unroll
      for (int r = 0; r < 4; ++r) {
        float v = sc4[mtl][nt][r];
        sc4[mtl][nt][r] = blk[nt] ? -10000.0f : v * scale;
      }
#pragma unroll
  for (int mtl = 0; mtl < 2; ++mtl) {
#pragma unroll
    for (int r = 0; r < 4; ++r) {
      float mx = fmaxf(fmaxf(sc4[mtl][0][r], sc4[mtl][1][r]),
                       fmaxf(sc4[mtl][2][r], sc4[mtl][3][r]));
#pragma unroll
      for (int off = 1; off < 16; off <<= 1) mx = fmaxf(mx, __shfl_xor(mx, off, 64));
      float e0 = __expf(sc4[mtl][0][r] - mx);
      float e1 = __expf(sc4[mtl][1][r] - mx);
      float e2 = __expf(sc4[mtl][2][r] - mx);
      float e3 = __expf(sc4[mtl][3][r] - mx);
      float sm = (e0 + e1) + (e2 + e3);
#pragma unroll
      for (int off = 1; off < 16; off <<= 1) sm += __shfl_xor(sm, off, 64);
      float inv = 1.0f / sm;
      int row = (mh * 2 + mtl) * 16 + quad * 4 + r;
      Ps[row * 68 +  0 + cl] = (__bf16)(e0 * inv);
      Ps[row * 68 + 16 + cl] = (__bf16)(e1 * inv);
      Ps[row * 68 + 32 + cl] = (__bf16)(e2 * inv);
      Ps[row * 68 + 48 + cl] = (__bf16)(e3 * inv);
    }
  }
  // no barrier: PV reads only this wave's own Ps rows; Vt ready since post-QKV sync

  // ---- phase 3: O = P @ V (this wave's 32 rows) ----
  f32x4 oacc[2][2];
  {
    bf16x8 bv[2][2];
#pragma unroll
    for (int nt = 0; nt < 2; ++nt)
#pragma unroll
      for (int kt = 0; kt < 2; ++kt)
        bv[nt][kt] = *(const bf16x8*)&Vts[(nt * 16 + cl) * 66 + kt * 32 + quad * 8];
    __builtin_amdgcn_s_setprio(1);
#pragma unroll
    for (int mtl = 0; mtl < 2; ++mtl) {
      int mt = mh * 2 + mtl;
      bf16x8 ap0 = *(const bf16x8*)&Ps[(mt * 16 + cl) * 68 + quad * 8];
      bf16x8 ap1 = *(const bf16x8*)&Ps[(mt * 16 + cl) * 68 + 32 + quad * 8];
#pragma unroll
      for (int nt = 0; nt < 2; ++nt) {
        f32x4 z = {0.f, 0.f, 0.f, 0.f};
        z = __builtin_amdgcn_mfma_f32_16x16x32_bf16(ap0, bv[nt][0], z, 0, 0, 0);
        z = __builtin_amdgcn_mfma_f32_16x16x32_bf16(ap1, bv[nt][1], z, 0, 0, 0);
        oacc[mtl][nt] = z;
      }
    }
    __builtin_amdgcn_s_setprio(0);
  }
  __syncthreads();  // all Ps/Vt reads done -> Os may overlay Ps
#pragma unroll
  for (int mtl = 0; mtl < 2; ++mtl)
#pragma unroll
    for (int nt = 0; nt < 2; ++nt)
#pragma unroll
      for (int r = 0; r < 4; ++r)
        Os[((mh * 2 + mtl) * 16 + quad * 4 + r) * 36 + nt * 16 + cl] = (__bf16)oacc[mtl][nt][r];
  __syncthreads();

  // ---- phase 4: proj (wave w owns 16 cols); fl==0 -> o; fl==1 -> y = xa+g1*o ----
  {
    const int col = w * 16 + cl;
    const float lwc = ln1w[col], lbc = ln1b[col], g1c = g1[col];
    bf16x8 bpr[4];
#pragma unroll
    for (int kt = 0; kt < 4; ++kt)
      bpr[kt] = *(const bf16x8*)&projt[(size_t)col * 128 + kt * 32 + quad * 8];
    const float pb = projb[col];
#pragma unroll
    for (int mt = 0; mt < 4; ++mt) {
      f32x4 acc = {pb, pb, pb, pb};
#pragma unroll
      for (int kt = 0; kt < 4; ++kt) {
        const __bf16* op = scratch + kt * 4352;  // head kt's O region
        bf16x8 a = *(const bf16x8*)&op[(mt * 16 + cl) * 36 + quad * 8];
        acc = __builtin_amdgcn_mfma_f32_16x16x32_bf16(a, bpr[kt], acc, 0, 0, 0);
      }
#pragma unroll
      for (int r = 0; r < 4; ++r) {
        int row = mt * 16 + quad * 4 + r;
        unsigned char f = fl[row];
        if (f == 0) {
          out[(size_t)srow[row] * 128 + col] = acc[r];
        } else if (f == 1) {
          size_t a = (size_t)srow[row] * 128 + col;
          float lnv = out[a];  // LN1 value, L2-hot from phase 0
          float xa = (lnv - sm2[row]) * si2[row] * lwc + lbc;
          out[a] = xa + g1c * acc[r];
        }
      }
    }
  }
}

// ---------------- MLP path: y already in out (written by k_attn phase 4) ----------------
// LDS: y2s bf16 64x136 (17408B) + hb bf16 64x68 (8704B) + wrs 256B = 26368B.
// Phase 0 = one gather + one LN2 chain per row.  Epilogue RMW: out = y + g2*z.
__global__ __launch_bounds__(256, 5) void k_mlp(
    const int* __restrict__ iw, const int* __restrict__ ia,
    const float* __restrict__ ln2w, const float* __restrict__ ln2b,
    const __bf16* __restrict__ w1t, const float* __restrict__ b1,
    const __bf16* __restrict__ w2t, const float* __restrict__ b2,
    const float* __restrict__ g2,
    float* out) {
  __shared__ __align__(16) __bf16 y2s[64 * 136];
  __shared__ __align__(16) __bf16 hb[64 * 68];
  __shared__ int wrs[64];

  const int tid = threadIdx.x;
  const int w = tid >> 6, lane = tid & 63;
  const int quad = lane >> 4, cl = lane & 15;

  if (tid < 64) {
    int s = ia[(blockIdx.x << 6) + tid];
    wrs[tid] = iw[s >> 6] * 64 + (s & 63);
  }
  __syncthreads();

  const float l2w0 = ln2w[2 * lane], l2w1 = ln2w[2 * lane + 1];
  const float l2b0 = ln2b[2 * lane], l2b1 = ln2b[2 * lane + 1];

  // ---- phase 0: gather y from out, LN2 -> y2s (bf16) ----
  for (int half = 0; half < 2; ++half) {
    float2 yv[8];
#pragma unroll
    for (int ii = 0; ii < 8; ++ii) {
      int r = w + 4 * (half * 8 + ii);
      yv[ii] = ((const float2*)(out + (size_t)wrs[r] * 128))[lane];
    }
#pragma unroll
    for (int ii = 0; ii < 8; ++ii) {
      int r = w + 4 * (half * 8 + ii);
      float mean = wave_sum(yv[ii].x + yv[ii].y) * (1.0f / 128.0f);
      float d0 = yv[ii].x - mean, d1 = yv[ii].y - mean;
      float inv = rsqrtf(wave_sum(d0 * d0 + d1 * d1) * (1.0f / 128.0f) + 1e-6f);
      bf16x2 p2;
      p2[0] = (__bf16)(d0 * inv * l2w0 + l2b0);
      p2[1] = (__bf16)(d1 * inv * l2w1 + l2b1);
      *(bf16x2*)&y2s[r * 136 + 2 * lane] = p2;
    }
  }
  __syncthreads();

  f32x4 zacc[4][2];
#pragma unroll
  for (int nt = 0; nt < 2; ++nt) {
    float bb = b2[w * 32 + nt * 16 + cl];
#pragma unroll
    for (int mt = 0; mt < 4; ++mt) zacc[mt][nt] = (f32x4){bb, bb, bb, bb};
  }

  for (int ch = 0; ch < 8; ++ch) {
    // ---- GEMM1 chunk: H[:, ch*64 + w*16 .. +16] = gelu(y2 @ W1 + b1) ----
    {
      int col = ch * 64 + w * 16 + cl;
      bf16x8 bfr[4];
#pragma unroll
      for (int kt = 0; kt < 4; ++kt)
        bfr[kt] = *(const bf16x8*)&w1t[(size_t)col * 128 + kt * 32 + quad * 8];
      float bias = b1[col];
      __builtin_amdgcn_s_setprio(1);
#pragma unroll
      for (int mt = 0; mt < 4; ++mt) {
        f32x4 acc = {bias, bias, bias, bias};
#pragma unroll
        for (int kt = 0; kt < 4; ++kt) {
          bf16x8 a = *(const bf16x8*)&y2s[(mt * 16 + cl) * 136 + kt * 32 + quad * 8];
          acc = __builtin_amdgcn_mfma_f32_16x16x32_bf16(a, bfr[kt], acc, 0, 0, 0);
        }
#pragma unroll
        for (int r = 0; r < 4; ++r) {
          float a = acc[r];
          float g = a * 0.5f * (1.0f + erff(a * 0.70710678118654752f));
          hb[(mt * 16 + quad * 4 + r) * 68 + w * 16 + cl] = (__bf16)g;
        }
      }
      __builtin_amdgcn_s_setprio(0);
    }
    __syncthreads();
    // ---- GEMM2 accumulate: Z[:, w*32 .. +32] += H_chunk(64) @ W2[ch*64.., :] ----
#pragma unroll
    for (int nt = 0; nt < 2; ++nt) {
      int col = w * 32 + nt * 16 + cl;
      bf16x8 bfr[2];
#pragma unroll
      for (int kk = 0; kk < 2; ++kk)
        bfr[kk] = *(const bf16x8*)&w2t[(size_t)col * 512 + ch * 64 + kk * 32 + quad * 8];
      __builtin_amdgcn_s_setprio(1);
#pragma unroll
      for (int mt = 0; mt < 4; ++mt)
#pragma unroll
        for (int kk = 0; kk < 2; ++kk) {
          bf16x8 a = *(const bf16x8*)&hb[(mt * 16 + cl) * 68 + kk * 32 + quad * 8];
          zacc[mt][nt] = __builtin_amdgcn_mfma_f32_16x16x32_bf16(a, bfr[kk],
                                                                zacc[mt][nt], 0, 0, 0);
        }
      __builtin_amdgcn_s_setprio(0);
    }
    __syncthreads();
  }

  // ---- epilogue: out = y + g2 * z  (y still in out) ----
#pragma unroll
  for (int mt = 0; mt < 4; ++mt)
#pragma unroll
    for (int nt = 0; nt < 2; ++nt) {
      int col = w * 32 + nt * 16 + cl;
      float gg = g2[col];
#pragma unroll
      for (int r = 0; r < 4; ++r) {
        int row = mt * 16 + quad * 4 + r;
        size_t a = (size_t)wrs[row] * 128 + col;
        out[a] = out[a] + gg * zacc[mt][nt][r];
      }
    }
}

extern "C" void kernel_launch(void* const* d_in, const int* in_sizes, int n_in,
                              void* d_out, int out_size, void* d_ws, size_t ws_size,
                              hipStream_t stream) {
  const float* x = (const float*)d_in[0];
  const int* iw = (const int*)d_in[1];
  const int* ip = (const int*)d_in[2];
  const int* ia = (const int*)d_in[3];
  const int* ib = (const int*)d_in[4];
  const float* ln1w = (const float*)d_in[7];
  const float* ln1b = (const float*)d_in[8];
  const float* qkvw = (const float*)d_in[9];
  const float* qkvb = (const float*)d_in[10];
  const float* projw = (const float*)d_in[11];
  const float* projb = (const float*)d_in[12];
  const float* g1 = (const float*)d_in[13];
  const float* ln2w = (const float*)d_in[14];
  const float* ln2b = (const float*)d_in[15];
  const float* w1 = (const float*)d_in[16];
  const float* b1 = (const float*)d_in[17];
  const float* w2 = (const float*)d_in[18];
  const float* b2 = (const float*)d_in[19];
  const float* g2 = (const float*)d_in[20];
  float* out = (float*)d_out;

  // ws layout: flags (MW_ B) | qkvt bf16 384x128 | projt bf16 128x128 |
  //            w1t bf16 512x128 | w2t bf16 128x512   (total 640 KB)
  unsigned char* flags = (unsigned char*)d_ws;
  __bf16* qkvt = (__bf16*)((char*)d_ws + MW_);
  __bf16* projt = (__bf16*)((char*)d_ws + MW_ + 384 * 128 * 2);
  __bf16* w1t = (__bf16*)((char*)d_ws + MW_ + 384 * 128 * 2 + 128 * 128 * 2);
  __bf16* w2t = (__bf16*)((char*)d_ws + MW_ + 384 * 128 * 2 + 128 * 128 * 2 + 512 * 128 * 2);

  k_set8<<<MW_ / 256, 256, 0, stream>>>(flags, MW_);
  k_scatter2<<<(A_ + BL_) / 256, 256, 0, stream>>>(flags, ia, ib);
  k_prep<<<(384 * 128 + 128 * 128 + 512 * 128 + 128 * 512) / 256, 256, 0, stream>>>(
      qkvw, projw, w1, w2, qkvt, projt, w1t, w2t);
  k_ln_all<<<NROWS_ / 8, 256, 0, stream>>>(x, ln1w, ln1b, out);
  k_attn<<<M_, 512, 0, stream>>>(iw, ip, flags, ln1w, ln1b, qkvt, qkvb,
                                 projt, projb, g1, out);
  k_mlp<<<A_ / 64, 256, 0, stream>>>(iw, ia, ln2w, ln2b,
                                     w1t, b1, w2t, b2, g2, out);
}

// Round 11
// 836.205 us; speedup vs baseline: 1.0262x; 1.0262x over previous
//
#include <hip/hip_runtime.h>
#include <hip/hip_bf16.h>
#include <math.h>

#define N_   8192
#define P_   64
#define C_   128
#define M_   4096
#define MW_  (M_ * P_)     // 262144
#define A_   131072
#define BL_  65536
#define NROWS_ (N_ * P_)   // 524288
#define LNBLK_   (NROWS_ / 8)        // 65536
#define PREPBLK_ (196608 / 256)      // 768
#define SETBLK_  (MW_ / 256)         // 1024

typedef __attribute__((ext_vector_type(8))) __bf16 bf16x8;
typedef __attribute__((ext_vector_type(4))) float f32x4;
typedef __attribute__((ext_vector_type(2))) __bf16 bf16x2;

__device__ __forceinline__ float wave_sum(float v) {
#pragma unroll
  for (int o = 32; o > 0; o >>= 1) v += __shfl_xor(v, o, 64);
  return v;
}

// ---------------- scatter flags (needs zeroed flags from k_ln_prep_set) ----------------
__global__ __launch_bounds__(256) void k_scatter2(unsigned char* p,
                                                  const int* __restrict__ ia,
                                                  const int* __restrict__ ib) {
  int i = blockIdx.x * 256 + threadIdx.x;
  if (i < A_) p[ia[i]] = 1;
  else {
    int j = i - A_;
    if (j < BL_) p[ib[j]] = 2;
  }
}

// ---------------- LN1 all rows + weight prep + flag zeroing, one launch ----------------
__global__ __launch_bounds__(256) void k_ln_prep_set(
    const float* __restrict__ x,
    const float* __restrict__ w, const float* __restrict__ b,
    const float* __restrict__ qkvw, const float* __restrict__ projw,
    const float* __restrict__ w1, const float* __restrict__ w2,
    __bf16* __restrict__ qkvt, __bf16* __restrict__ projt,
    __bf16* __restrict__ w1t, __bf16* __restrict__ w2t,
    unsigned char* __restrict__ flags,
    float* __restrict__ out) {
  if (blockIdx.x >= LNBLK_) {
    int bx = blockIdx.x - LNBLK_;
    if (bx >= PREPBLK_) {
      int i = (bx - PREPBLK_) * 256 + threadIdx.x;
      flags[i] = 0;
      return;
    }
    int i = bx * 256 + threadIdx.x;
    if (i < 384 * 128) {
      int col = i >> 7, row = i & 127;
      qkvt[i] = (__bf16)qkvw[row * 384 + col];
    } else if (i < 384 * 128 + 128 * 128) {
      int j = i - 384 * 128;
      int col = j >> 7, row = j & 127;
      projt[j] = (__bf16)projw[row * 128 + col];
    } else if (i < 384 * 128 + 128 * 128 + 512 * 128) {
      int j = i - 384 * 128 - 128 * 128;
      int col = j >> 7, row = j & 127;
      w1t[j] = (__bf16)w1[row * 512 + col];
    } else {
      int j = i - 384 * 128 - 128 * 128 - 512 * 128;
      int col = j >> 9, row = j & 511;
      w2t[j] = (__bf16)w2[row * 128 + col];
    }
    return;
  }
  int hw = threadIdx.x >> 5, l = threadIdx.x & 31;
  size_t row = (size_t)blockIdx.x * 8 + hw;
  float4 v = ((const float4*)(x + row * 128))[l];
  float s = (v.x + v.y) + (v.z + v.w);
#pragma unroll
  for (int o = 1; o < 32; o <<= 1) s += __shfl_xor(s, o, 64);
  float mean = s * (1.0f / 128.0f);
  float d0 = v.x - mean, d1 = v.y - mean, d2 = v.z - mean, d3 = v.w - mean;
  float q = (d0 * d0 + d1 * d1) + (d2 * d2 + d3 * d3);
#pragma unroll
  for (int o = 1; o < 32; o <<= 1) q += __shfl_xor(q, o, 64);
  float inv = rsqrtf(q * (1.0f / 128.0f) + 1e-6f);
  float4 wv = ((const float4*)w)[l];
  float4 bv = ((const float4*)b)[l];
  float4 o4;
  o4.x = d0 * inv * wv.x + bv.x;
  o4.y = d1 * inv * wv.y + bv.y;
  o4.z = d2 * inv * wv.z + bv.z;
  o4.w = d3 * inv * wv.w + bv.w;
  ((float4*)(out + row * 128))[l] = o4;
}

// ---------------- attention: one block per partition, MFMA (R6 structure, 223us) ----------------
// LDS (3 blocks/CU): XV 64x132 bf16 (16896B; Xs, then Vt[4][32][66] overlay)
//  + scratch 4x4352 (Q[64][34]+K[64][34]; Ps[64][68] overlay; Os[64][36])
//  = 34816B + srow/fl 320B => 52032B; x3 = 156KB < 160KB.
// R5/R10 lessons: 8-wave split loses (barriers > occupancy gain); tight VGPR caps spill.
// R7/R9 lessons: fusing MLP work here is net-zero or worse -- keep attn minimal.
__global__ __launch_bounds__(256, 3) void k_attn(
    const int* __restrict__ iw,
    const int* __restrict__ ip, const unsigned char* __restrict__ flags,
    const float* __restrict__ ln1w, const float* __restrict__ ln1b,
    const __bf16* __restrict__ qkvt, const float* __restrict__ qkvb,
    const __bf16* __restrict__ projt, const float* __restrict__ projb,
    float* out) {
  __shared__ __align__(16) __bf16 XV[64 * 132];
  __shared__ __align__(16) __bf16 scratch[4 * 4352];
  __shared__ int srow[64];
  __shared__ unsigned char fl[64];

  const int tid = threadIdx.x;
  const int w = tid >> 6, lane = tid & 63;
  const int quad = lane >> 4, cl = lane & 15;
  const int m = blockIdx.x;

  if (tid < 64) {
    int s = ip[(m << 6) + tid];
    fl[tid] = flags[s];
    srow[tid] = iw[s >> 6] * 64 + (s & 63);
  }
  __syncthreads();

  __bf16* Xs = XV;
  const float lw0 = ln1w[2 * lane], lw1 = ln1w[2 * lane + 1];
  const float lb0 = ln1b[2 * lane], lb1 = ln1b[2 * lane + 1];

  // ---- phase 0: gather LN1 rows from out; re-LN asy only ----
  {
    float2 xv[16];
#pragma unroll
    for (int ii = 0; ii < 16; ++ii) {
      int r = w + 4 * ii;
      xv[ii] = ((const float2*)(out + (size_t)srow[r] * 128))[lane];
    }
#pragma unroll
    for (int ii = 0; ii < 16; ++ii) {
      int r = w + 4 * ii;
      float y0 = xv[ii].x, y1 = xv[ii].y;
      if (fl[r] == 1) {
        float mean = wave_sum(y0 + y1) * (1.0f / 128.0f);
        float d0 = y0 - mean, d1 = y1 - mean;
        float inv = rsqrtf(wave_sum(d0 * d0 + d1 * d1) * (1.0f / 128.0f) + 1e-6f);
        y0 = d0 * inv * lw0 + lb0;
        y1 = d1 * inv * lw1 + lb1;
      }
      bf16x2 p2;
      p2[0] = (__bf16)y0; p2[1] = (__bf16)y1;
      *(bf16x2*)&Xs[r * 132 + 2 * lane] = p2;
    }
  }
  __syncthreads();

  __bf16* wsc = scratch + w * 4352;
  __bf16* Qs  = wsc;           // [64][34]
  __bf16* Ks  = wsc + 2176;    // [64][34]
  __bf16* Vts = XV + w * 2112; // [32][66] overlays dead Xs
  __bf16* Ps  = wsc;           // [64][68] overlays Q+K
  __bf16* Os  = wsc;           // [64][36] overlays Ps
  const int h = w;

  // ---- phase 1: QKV ----
  bf16x8 af[4][4];
#pragma unroll
  for (int mt = 0; mt < 4; ++mt)
#pragma unroll
    for (int kt = 0; kt < 4; ++kt)
      af[mt][kt] = *(const bf16x8*)&Xs[(mt * 16 + cl) * 132 + kt * 32 + quad * 8];
  __syncthreads();

#pragma unroll
  for (int t = 0; t < 3; ++t) {
#pragma unroll
    for (int nt = 0; nt < 2; ++nt) {
      int col = h * 96 + t * 32 + nt * 16 + cl;
      bf16x8 bfr[4];
#pragma unroll
      for (int kt = 0; kt < 4; ++kt)
        bfr[kt] = *(const bf16x8*)&qkvt[(size_t)col * 128 + kt * 32 + quad * 8];
      float bias = qkvb[col];
      __builtin_amdgcn_s_setprio(1);
#pragma unroll
      for (int mt = 0; mt < 4; ++mt) {
        f32x4 acc = {bias, bias, bias, bias};
#pragma unroll
        for (int kt = 0; kt < 4; ++kt)
          acc = __builtin_amdgcn_mfma_f32_16x16x32_bf16(af[mt][kt], bfr[kt], acc, 0, 0, 0);
        if (t == 0) {
#pragma unroll
          for (int r = 0; r < 4; ++r)
            Qs[(mt * 16 + quad * 4 + r) * 34 + nt * 16 + cl] = (__bf16)acc[r];
        } else if (t == 1) {
#pragma unroll
          for (int r = 0; r < 4; ++r)
            Ks[(mt * 16 + quad * 4 + r) * 34 + nt * 16 + cl] = (__bf16)acc[r];
        } else {
#pragma unroll
          for (int r = 0; r < 4; ++r)
            Vts[(nt * 16 + cl) * 66 + mt * 16 + quad * 4 + r] = (__bf16)acc[r];
        }
      }
      __builtin_amdgcn_s_setprio(0);
    }
  }

  // ---- phase 2: S = Q K^T, mask, softmax ----
  f32x4 sc4[4][4];
  {
    bf16x8 bk[4];
#pragma unroll
    for (int nt = 0; nt < 4; ++nt)
      bk[nt] = *(const bf16x8*)&Ks[(nt * 16 + cl) * 34 + quad * 8];
    __builtin_amdgcn_s_setprio(1);
#pragma unroll
    for (int mt = 0; mt < 4; ++mt) {
      bf16x8 aq = *(const bf16x8*)&Qs[(mt * 16 + cl) * 34 + quad * 8];
#pragma unroll
      for (int nt = 0; nt < 4; ++nt) {
        f32x4 z = {0.f, 0.f, 0.f, 0.f};
        sc4[mt][nt] = __builtin_amdgcn_mfma_f32_16x16x32_bf16(aq, bk[nt], z, 0, 0, 0);
      }
    }
    __builtin_amdgcn_s_setprio(0);
  }
  const float scale = 0.17677669529663687f;
  bool blk[4];
#pragma unroll
  for (int nt = 0; nt < 4; ++nt) blk[nt] = (fl[nt * 16 + cl] == 2);
#pragma unroll
  for (int mt = 0; mt < 4; ++mt)
#pragma unroll
    for (int nt = 0; nt < 4; ++nt)
#pragma unroll
      for (int r = 0; r < 4; ++r) {
        float v = sc4[mt][nt][r];
        sc4[mt][nt][r] = blk[nt] ? -10000.0f : v * scale;
      }
#pragma unroll
  for (int mt = 0; mt < 4; ++mt) {
#pragma unroll
    for (int r = 0; r < 4; ++r) {
      float mx = fmaxf(fmaxf(sc4[mt][0][r], sc4[mt][1][r]),
                       fmaxf(sc4[mt][2][r], sc4[mt][3][r]));
#pragma unroll
      for (int off = 1; off < 16; off <<= 1) mx = fmaxf(mx, __shfl_xor(mx, off, 64));
      float e0 = __expf(sc4[mt][0][r] - mx);
      float e1 = __expf(sc4[mt][1][r] - mx);
      float e2 = __expf(sc4[mt][2][r] - mx);
      float e3 = __expf(sc4[mt][3][r] - mx);
      float sm = (e0 + e1) + (e2 + e3);
#pragma unroll
      for (int off = 1; off < 16; off <<= 1) sm += __shfl_xor(sm, off, 64);
      float inv = 1.0f / sm;
      int row = mt * 16 + quad * 4 + r;
      Ps[row * 68 +  0 + cl] = (__bf16)(e0 * inv);
      Ps[row * 68 + 16 + cl] = (__bf16)(e1 * inv);
      Ps[row * 68 + 32 + cl] = (__bf16)(e2 * inv);
      Ps[row * 68 + 48 + cl] = (__bf16)(e3 * inv);
    }
  }

  // ---- phase 3: O = P V ----
  f32x4 oacc[4][2];
  {
    bf16x8 bv[2][2];
#pragma unroll
    for (int nt = 0; nt < 2; ++nt)
#pragma unroll
      for (int kt = 0; kt < 2; ++kt)
        bv[nt][kt] = *(const bf16x8*)&Vts[(nt * 16 + cl) * 66 + kt * 32 + quad * 8];
    __builtin_amdgcn_s_setprio(1);
#pragma unroll
    for (int mt = 0; mt < 4; ++mt) {
      bf16x8 ap0 = *(const bf16x8*)&Ps[(mt * 16 + cl) * 68 + quad * 8];
      bf16x8 ap1 = *(const bf16x8*)&Ps[(mt * 16 + cl) * 68 + 32 + quad * 8];
#pragma unroll
      for (int nt = 0; nt < 2; ++nt) {
        f32x4 z = {0.f, 0.f, 0.f, 0.f};
        z = __builtin_amdgcn_mfma_f32_16x16x32_bf16(ap0, bv[nt][0], z, 0, 0, 0);
        z = __builtin_amdgcn_mfma_f32_16x16x32_bf16(ap1, bv[nt][1], z, 0, 0, 0);
        oacc[mt][nt] = z;
      }
    }
    __builtin_amdgcn_s_setprio(0);
  }
#pragma unroll
  for (int mt = 0; mt < 4; ++mt)
#pragma unroll
    for (int nt = 0; nt < 2; ++nt)
#pragma unroll
      for (int r = 0; r < 4; ++r)
        Os[(mt * 16 + quad * 4 + r) * 36 + nt * 16 + cl] = (__bf16)oacc[mt][nt][r];
  __syncthreads();

  // ---- phase 4: proj, wave w owns 32 cols; write o for fl!=2 ----
  const int jw = w * 32;
#pragma unroll
  for (int mt = 0; mt < 4; ++mt) {
#pragma unroll
    for (int nt = 0; nt < 2; ++nt) {
      int col = jw + nt * 16 + cl;
      float pb = projb[col];
      f32x4 acc = {pb, pb, pb, pb};
#pragma unroll
      for (int kt = 0; kt < 4; ++kt) {
        const __bf16* op = scratch + kt * 4352;
        bf16x8 a = *(const bf16x8*)&op[(mt * 16 + cl) * 36 + quad * 8];
        bf16x8 bb = *(const bf16x8*)&projt[(size_t)col * 128 + kt * 32 + quad * 8];
        acc = __builtin_amdgcn_mfma_f32_16x16x32_bf16(a, bb, acc, 0, 0, 0);
      }
#pragma unroll
      for (int r = 0; r < 4; ++r) {
        int row = mt * 16 + quad * 4 + r;
        if (fl[row] != 2)
          out[(size_t)srow[row] * 128 + col] = acc[r];
      }
    }
  }
}

// ---------------- MLP path: BM=128 rows/block (1024 blocks) ----------------
// LDS: y2s bf16 128x136 (34816B) + hb bf16 128x68 (17408B) + wrs 512B = 52736B
//  => 3 blocks/CU (LDS-bound; R6 showed mlp is occupancy-insensitive).
// Doubled M-tile: each weight fragment load feeds 8 mt (2x MFMA density),
// per-row barrier and L2-latency cost halves.  Park-y + RMW epilogue (R6 proven).
// launch_bounds(256,3) -> VGPR cap ~168: zacc[8][2]=64 + work ~120, no spills.
__global__ __launch_bounds__(256, 3) void k_mlp(
    const float* __restrict__ x, const int* __restrict__ iw,
    const int* __restrict__ ia,
    const float* __restrict__ ln1w, const float* __restrict__ ln1b,
    const float* __restrict__ g1,
    const float* __restrict__ ln2w, const float* __restrict__ ln2b,
    const __bf16* __restrict__ w1t, const float* __restrict__ b1,
    const __bf16* __restrict__ w2t, const float* __restrict__ b2,
    const float* __restrict__ g2,
    float* out) {
  __shared__ __align__(16) __bf16 y2s[128 * 136];
  __shared__ __align__(16) __bf16 hb[128 * 68];
  __shared__ int wrs[128];

  const int tid = threadIdx.x;
  const int w = tid >> 6, lane = tid & 63;
  const int quad = lane >> 4, cl = lane & 15;

  if (tid < 128) {
    int s = ia[(blockIdx.x << 7) + tid];
    wrs[tid] = iw[s >> 6] * 64 + (s & 63);
  }
  __syncthreads();

  const float lw0 = ln1w[2 * lane], lw1 = ln1w[2 * lane + 1];
  const float lb0 = ln1b[2 * lane], lb1 = ln1b[2 * lane + 1];
  const float g1a = g1[2 * lane], g1b = g1[2 * lane + 1];
  const float l2w0 = ln2w[2 * lane], l2w1 = ln2w[2 * lane + 1];
  const float l2b0 = ln2b[2 * lane], l2b1 = ln2b[2 * lane + 1];

  // ---- phase 0: gather + LN1(LN1(x)) + residual(o from out) -> park y; LN2 -> y2s ----
  for (int q = 0; q < 8; ++q) {
    float2 xv[4], ov[4];
#pragma unroll
    for (int ii = 0; ii < 4; ++ii) {
      int r = w + 4 * (q * 4 + ii);
      size_t wr = (size_t)wrs[r];
      xv[ii] = ((const float2*)(x + wr * 128))[lane];
      ov[ii] = ((const float2*)(out + wr * 128))[lane];
    }
#pragma unroll
    for (int ii = 0; ii < 4; ++ii) {
      int r = w + 4 * (q * 4 + ii);
      float mean = wave_sum(xv[ii].x + xv[ii].y) * (1.0f / 128.0f);
      float d0 = xv[ii].x - mean, d1 = xv[ii].y - mean;
      float inv = rsqrtf(wave_sum(d0 * d0 + d1 * d1) * (1.0f / 128.0f) + 1e-6f);
      float y0 = d0 * inv * lw0 + lb0, y1 = d1 * inv * lw1 + lb1;
      mean = wave_sum(y0 + y1) * (1.0f / 128.0f);
      d0 = y0 - mean; d1 = y1 - mean;
      inv = rsqrtf(wave_sum(d0 * d0 + d1 * d1) * (1.0f / 128.0f) + 1e-6f);
      float xa0 = d0 * inv * lw0 + lb0, xa1 = d1 * inv * lw1 + lb1;
      float yv0 = xa0 + g1a * ov[ii].x;
      float yv1 = xa1 + g1b * ov[ii].y;
      ((float2*)(out + (size_t)wrs[r] * 128))[lane] = make_float2(yv0, yv1);  // park y
      mean = wave_sum(yv0 + yv1) * (1.0f / 128.0f);
      d0 = yv0 - mean; d1 = yv1 - mean;
      inv = rsqrtf(wave_sum(d0 * d0 + d1 * d1) * (1.0f / 128.0f) + 1e-6f);
      bf16x2 p2;
      p2[0] = (__bf16)(d0 * inv * l2w0 + l2b0);
      p2[1] = (__bf16)(d1 * inv * l2w1 + l2b1);
      *(bf16x2*)&y2s[r * 136 + 2 * lane] = p2;
    }
  }
  __threadfence_block();
  __syncthreads();

  f32x4 zacc[8][2];
#pragma unroll
  for (int nt = 0; nt < 2; ++nt) {
    float bb = b2[w * 32 + nt * 16 + cl];
#pragma unroll
    for (int mt = 0; mt < 8; ++mt) zacc[mt][nt] = (f32x4){bb, bb, bb, bb};
  }

  for (int ch = 0; ch < 8; ++ch) {
    // ---- GEMM1 chunk: H[:, ch*64 + w*16 .. +16] = gelu(y2 @ W1 + b1), 128 rows ----
    {
      int col = ch * 64 + w * 16 + cl;
      bf16x8 bfr[4];
#pragma unroll
      for (int kt = 0; kt < 4; ++kt)
        bfr[kt] = *(const bf16x8*)&w1t[(size_t)col * 128 + kt * 32 + quad * 8];
      float bias = b1[col];
      __builtin_amdgcn_s_setprio(1);
#pragma unroll
      for (int mt = 0; mt < 8; ++mt) {
        f32x4 acc = {bias, bias, bias, bias};
#pragma unroll
        for (int kt = 0; kt < 4; ++kt) {
          bf16x8 a = *(const bf16x8*)&y2s[(mt * 16 + cl) * 136 + kt * 32 + quad * 8];
          acc = __builtin_amdgcn_mfma_f32_16x16x32_bf16(a, bfr[kt], acc, 0, 0, 0);
        }
#pragma unroll
        for (int r = 0; r < 4; ++r) {
          float a = acc[r];
          float g = a * 0.5f * (1.0f + erff(a * 0.70710678118654752f));
          hb[(mt * 16 + quad * 4 + r) * 68 + w * 16 + cl] = (__bf16)g;
        }
      }
      __builtin_amdgcn_s_setprio(0);
    }
    __syncthreads();
    // ---- GEMM2 accumulate: Z[:, w*32 .. +32] += H_chunk(64) @ W2[ch*64.., :] ----
#pragma unroll
    for (int nt = 0; nt < 2; ++nt) {
      int col = w * 32 + nt * 16 + cl;
      bf16x8 bfr[2];
#pragma unroll
      for (int kk = 0; kk < 2; ++kk)
        bfr[kk] = *(const bf16x8*)&w2t[(size_t)col * 512 + ch * 64 + kk * 32 + quad * 8];
      __builtin_amdgcn_s_setprio(1);
#pragma unroll
      for (int mt = 0; mt < 8; ++mt)
#pragma unroll
        for (int kk = 0; kk < 2; ++kk) {
          bf16x8 a = *(const bf16x8*)&hb[(mt * 16 + cl) * 68 + kk * 32 + quad * 8];
          zacc[mt][nt] = __builtin_amdgcn_mfma_f32_16x16x32_bf16(a, bfr[kk],
                                                                zacc[mt][nt], 0, 0, 0);
        }
      __builtin_amdgcn_s_setprio(0);
    }
    __syncthreads();
  }

  // ---- epilogue: out = y + g2 * z  (y parked in out) ----
#pragma unroll
  for (int mt = 0; mt < 8; ++mt)
#pragma unroll
    for (int nt = 0; nt < 2; ++nt) {
      int col = w * 32 + nt * 16 + cl;
      float gg = g2[col];
#pragma unroll
      for (int r = 0; r < 4; ++r) {
        int row = mt * 16 + quad * 4 + r;
        size_t a = (size_t)wrs[row] * 128 + col;
        out[a] = out[a] + gg * zacc[mt][nt][r];
      }
    }
}

extern "C" void kernel_launch(void* const* d_in, const int* in_sizes, int n_in,
                              void* d_out, int out_size, void* d_ws, size_t ws_size,
                              hipStream_t stream) {
  const float* x = (const float*)d_in[0];
  const int* iw = (const int*)d_in[1];
  const int* ip = (const int*)d_in[2];
  const int* ia = (const int*)d_in[3];
  const int* ib = (const int*)d_in[4];
  const float* ln1w = (const float*)d_in[7];
  const float* ln1b = (const float*)d_in[8];
  const float* qkvw = (const float*)d_in[9];
  const float* qkvb = (const float*)d_in[10];
  const float* projw = (const float*)d_in[11];
  const float* projb = (const float*)d_in[12];
  const float* g1 = (const float*)d_in[13];
  const float* ln2w = (const float*)d_in[14];
  const float* ln2b = (const float*)d_in[15];
  const float* w1 = (const float*)d_in[16];
  const float* b1 = (const float*)d_in[17];
  const float* w2 = (const float*)d_in[18];
  const float* b2 = (const float*)d_in[19];
  const float* g2 = (const float*)d_in[20];
  float* out = (float*)d_out;

  // ws layout: flags (MW_ B) | qkvt bf16 384x128 | projt bf16 128x128 |
  //            w1t bf16 512x128 | w2t bf16 128x512   (total 640 KB)
  unsigned char* flags = (unsigned char*)d_ws;
  __bf16* qkvt = (__bf16*)((char*)d_ws + MW_);
  __bf16* projt = (__bf16*)((char*)d_ws + MW_ + 384 * 128 * 2);
  __bf16* w1t = (__bf16*)((char*)d_ws + MW_ + 384 * 128 * 2 + 128 * 128 * 2);
  __bf16* w2t = (__bf16*)((char*)d_ws + MW_ + 384 * 128 * 2 + 128 * 128 * 2 + 512 * 128 * 2);

  k_ln_prep_set<<<LNBLK_ + PREPBLK_ + SETBLK_, 256, 0, stream>>>(
      x, ln1w, ln1b, qkvw, projw, w1, w2, qkvt, projt, w1t, w2t, flags, out);
  k_scatter2<<<(A_ + BL_) / 256, 256, 0, stream>>>(flags, ia, ib);
  k_attn<<<M_, 256, 0, stream>>>(iw, ip, flags, ln1w, ln1b, qkvt, qkvb,
                                 projt, projb, out);
  k_mlp<<<A_ / 128, 256, 0, stream>>>(x, iw, ia, ln1w, ln1b, g1, ln2w, ln2b,
                                      w1t, b1, w2t, b2, g2, out);
}

// Round 12
// 769.656 us; speedup vs baseline: 1.1149x; 1.0865x over previous
//
#include <hip/hip_runtime.h>
#include <hip/hip_bf16.h>
#include <math.h>

#define N_   8192
#define P_   64
#define C_   128
#define M_   4096
#define MW_  (M_ * P_)     // 262144
#define A_   131072
#define BL_  65536
#define NROWS_ (N_ * P_)   // 524288
#define LNBLK_   (NROWS_ / 8)        // 65536
#define PREPBLK_ (196608 / 256)      // 768
#define SETBLK_  (MW_ / 256)         // 1024

typedef __attribute__((ext_vector_type(8))) __bf16 bf16x8;
typedef __attribute__((ext_vector_type(4))) __bf16 bf16x4;
typedef __attribute__((ext_vector_type(4))) float f32x4;
typedef __attribute__((ext_vector_type(2))) __bf16 bf16x2;

__device__ __forceinline__ float wave_sum(float v) {
#pragma unroll
  for (int o = 32; o > 0; o >>= 1) v += __shfl_xor(v, o, 64);
  return v;
}
// 32-lane (half-wave) reduction: offsets 1..16 stay within the half
__device__ __forceinline__ float half_sum(float v) {
#pragma unroll
  for (int o = 1; o < 32; o <<= 1) v += __shfl_xor(v, o, 64);
  return v;
}

// ---------------- scatter flags (needs zeroed flags from k_ln_prep_set) ----------------
__global__ __launch_bounds__(256) void k_scatter2(unsigned char* p,
                                                  const int* __restrict__ ia,
                                                  const int* __restrict__ ib) {
  int i = blockIdx.x * 256 + threadIdx.x;
  if (i < A_) p[ia[i]] = 1;
  else {
    int j = i - A_;
    if (j < BL_) p[ib[j]] = 2;
  }
}

// ---------------- LN1 all rows + weight prep + flag zeroing, one launch ----------------
__global__ __launch_bounds__(256) void k_ln_prep_set(
    const float* __restrict__ x,
    const float* __restrict__ w, const float* __restrict__ b,
    const float* __restrict__ qkvw, const float* __restrict__ projw,
    const float* __restrict__ w1, const float* __restrict__ w2,
    __bf16* __restrict__ qkvt, __bf16* __restrict__ projt,
    __bf16* __restrict__ w1t, __bf16* __restrict__ w2t,
    unsigned char* __restrict__ flags,
    float* __restrict__ out) {
  if (blockIdx.x >= LNBLK_) {
    int bx = blockIdx.x - LNBLK_;
    if (bx >= PREPBLK_) {
      int i = (bx - PREPBLK_) * 256 + threadIdx.x;
      flags[i] = 0;
      return;
    }
    int i = bx * 256 + threadIdx.x;
    if (i < 384 * 128) {
      int col = i >> 7, row = i & 127;
      qkvt[i] = (__bf16)qkvw[row * 384 + col];
    } else if (i < 384 * 128 + 128 * 128) {
      int j = i - 384 * 128;
      int col = j >> 7, row = j & 127;
      projt[j] = (__bf16)projw[row * 128 + col];
    } else if (i < 384 * 128 + 128 * 128 + 512 * 128) {
      int j = i - 384 * 128 - 128 * 128;
      int col = j >> 7, row = j & 127;
      w1t[j] = (__bf16)w1[row * 512 + col];
    } else {
      int j = i - 384 * 128 - 128 * 128 - 512 * 128;
      int col = j >> 9, row = j & 511;
      w2t[j] = (__bf16)w2[row * 128 + col];
    }
    return;
  }
  int hw = threadIdx.x >> 5, l = threadIdx.x & 31;
  size_t row = (size_t)blockIdx.x * 8 + hw;
  float4 v = ((const float4*)(x + row * 128))[l];
  float s = (v.x + v.y) + (v.z + v.w);
#pragma unroll
  for (int o = 1; o < 32; o <<= 1) s += __shfl_xor(s, o, 64);
  float mean = s * (1.0f / 128.0f);
  float d0 = v.x - mean, d1 = v.y - mean, d2 = v.z - mean, d3 = v.w - mean;
  float q = (d0 * d0 + d1 * d1) + (d2 * d2 + d3 * d3);
#pragma unroll
  for (int o = 1; o < 32; o <<= 1) q += __shfl_xor(q, o, 64);
  float inv = rsqrtf(q * (1.0f / 128.0f) + 1e-6f);
  float4 wv = ((const float4*)w)[l];
  float4 bv = ((const float4*)b)[l];
  float4 o4;
  o4.x = d0 * inv * wv.x + bv.x;
  o4.y = d1 * inv * wv.y + bv.y;
  o4.z = d2 * inv * wv.z + bv.z;
  o4.w = d3 * inv * wv.w + bv.w;
  ((float4*)(out + row * 128))[l] = o4;
}

// ---------------- attention: one block per partition, MFMA (R6 structure) ----------------
// LDS (3 blocks/CU): XV 64x132 bf16 (16896B; Xs, then Vt[4][32][66] overlay)
//  + scratch 4x4352 (Q[64][34]+K[64][34]; Ps[64][68] overlay; Os[64][36])
//  = 34816B + srow/fl 320B => 52032B; x3 = 156KB < 160KB.
// Phase 0 uses float4 (one row per half-wave; 5-step shuffle chains, 8 load insts).
// Lessons: R5/R10 8-wave split loses; R7/R9 MLP fusion is net-zero/worse;
// R5 tight VGPR caps spill; R11 BM=128 mlp loses.
__global__ __launch_bounds__(256, 3) void k_attn(
    const int* __restrict__ iw,
    const int* __restrict__ ip, const unsigned char* __restrict__ flags,
    const float* __restrict__ ln1w, const float* __restrict__ ln1b,
    const __bf16* __restrict__ qkvt, const float* __restrict__ qkvb,
    const __bf16* __restrict__ projt, const float* __restrict__ projb,
    float* out) {
  __shared__ __align__(16) __bf16 XV[64 * 132];
  __shared__ __align__(16) __bf16 scratch[4 * 4352];
  __shared__ int srow[64];
  __shared__ unsigned char fl[64];

  const int tid = threadIdx.x;
  const int w = tid >> 6, lane = tid & 63;
  const int quad = lane >> 4, cl = lane & 15;
  const int half = lane >> 5, l32 = lane & 31;
  const int m = blockIdx.x;

  if (tid < 64) {
    int s = ip[(m << 6) + tid];
    fl[tid] = flags[s];
    srow[tid] = iw[s >> 6] * 64 + (s & 63);
  }
  __syncthreads();

  __bf16* Xs = XV;

  // ---- phase 0: gather LN1 rows from out (float4, row per half-wave); re-LN asy ----
  {
    const float4 lw4 = ((const float4*)ln1w)[l32];
    const float4 lb4 = ((const float4*)ln1b)[l32];
    float4 xv[8];
#pragma unroll
    for (int ii = 0; ii < 8; ++ii) {
      int r = w * 16 + ii * 2 + half;
      xv[ii] = ((const float4*)(out + (size_t)srow[r] * 128))[l32];
    }
#pragma unroll
    for (int ii = 0; ii < 8; ++ii) {
      int r = w * 16 + ii * 2 + half;
      float4 v = xv[ii];
      if (fl[r] == 1) {
        float mean = half_sum((v.x + v.y) + (v.z + v.w)) * (1.0f / 128.0f);
        float d0 = v.x - mean, d1 = v.y - mean, d2 = v.z - mean, d3 = v.w - mean;
        float inv = rsqrtf(half_sum((d0 * d0 + d1 * d1) + (d2 * d2 + d3 * d3)) *
                               (1.0f / 128.0f) + 1e-6f);
        v.x = d0 * inv * lw4.x + lb4.x;
        v.y = d1 * inv * lw4.y + lb4.y;
        v.z = d2 * inv * lw4.z + lb4.z;
        v.w = d3 * inv * lw4.w + lb4.w;
      }
      bf16x4 p4;
      p4[0] = (__bf16)v.x; p4[1] = (__bf16)v.y;
      p4[2] = (__bf16)v.z; p4[3] = (__bf16)v.w;
      *(bf16x4*)&Xs[r * 132 + l32 * 4] = p4;
    }
  }
  __syncthreads();

  __bf16* wsc = scratch + w * 4352;
  __bf16* Qs  = wsc;           // [64][34]
  __bf16* Ks  = wsc + 2176;    // [64][34]
  __bf16* Vts = XV + w * 2112; // [32][66] overlays dead Xs
  __bf16* Ps  = wsc;           // [64][68] overlays Q+K
  __bf16* Os  = wsc;           // [64][36] overlays Ps
  const int h = w;

  // ---- phase 1: QKV ----
  bf16x8 af[4][4];
#pragma unroll
  for (int mt = 0; mt < 4; ++mt)
#pragma unroll
    for (int kt = 0; kt < 4; ++kt)
      af[mt][kt] = *(const bf16x8*)&Xs[(mt * 16 + cl) * 132 + kt * 32 + quad * 8];
  __syncthreads();

#pragma unroll
  for (int t = 0; t < 3; ++t) {
#pragma unroll
    for (int nt = 0; nt < 2; ++nt) {
      int col = h * 96 + t * 32 + nt * 16 + cl;
      bf16x8 bfr[4];
#pragma unroll
      for (int kt = 0; kt < 4; ++kt)
        bfr[kt] = *(const bf16x8*)&qkvt[(size_t)col * 128 + kt * 32 + quad * 8];
      float bias = qkvb[col];
      __builtin_amdgcn_s_setprio(1);
#pragma unroll
      for (int mt = 0; mt < 4; ++mt) {
        f32x4 acc = {bias, bias, bias, bias};
#pragma unroll
        for (int kt = 0; kt < 4; ++kt)
          acc = __builtin_amdgcn_mfma_f32_16x16x32_bf16(af[mt][kt], bfr[kt], acc, 0, 0, 0);
        if (t == 0) {
#pragma unroll
          for (int r = 0; r < 4; ++r)
            Qs[(mt * 16 + quad * 4 + r) * 34 + nt * 16 + cl] = (__bf16)acc[r];
        } else if (t == 1) {
#pragma unroll
          for (int r = 0; r < 4; ++r)
            Ks[(mt * 16 + quad * 4 + r) * 34 + nt * 16 + cl] = (__bf16)acc[r];
        } else {
#pragma unroll
          for (int r = 0; r < 4; ++r)
            Vts[(nt * 16 + cl) * 66 + mt * 16 + quad * 4 + r] = (__bf16)acc[r];
        }
      }
      __builtin_amdgcn_s_setprio(0);
    }
  }

  // ---- phase 2: S = Q K^T, mask, softmax ----
  f32x4 sc4[4][4];
  {
    bf16x8 bk[4];
#pragma unroll
    for (int nt = 0; nt < 4; ++nt)
      bk[nt] = *(const bf16x8*)&Ks[(nt * 16 + cl) * 34 + quad * 8];
    __builtin_amdgcn_s_setprio(1);
#pragma unroll
    for (int mt = 0; mt < 4; ++mt) {
      bf16x8 aq = *(const bf16x8*)&Qs[(mt * 16 + cl) * 34 + quad * 8];
#pragma unroll
      for (int nt = 0; nt < 4; ++nt) {
        f32x4 z = {0.f, 0.f, 0.f, 0.f};
        sc4[mt][nt] = __builtin_amdgcn_mfma_f32_16x16x32_bf16(aq, bk[nt], z, 0, 0, 0);
      }
    }
    __builtin_amdgcn_s_setprio(0);
  }
  const float scale = 0.17677669529663687f;
  bool blk[4];
#pragma unroll
  for (int nt = 0; nt < 4; ++nt) blk[nt] = (fl[nt * 16 + cl] == 2);
#pragma unroll
  for (int mt = 0; mt < 4; ++mt)
#pragma unroll
    for (int nt = 0; nt < 4; ++nt)
#pragma unroll
      for (int r = 0; r < 4; ++r) {
        float v = sc4[mt][nt][r];
        sc4[mt][nt][r] = blk[nt] ? -10000.0f : v * scale;
      }
#pragma unroll
  for (int mt = 0; mt < 4; ++mt) {
#pragma unroll
    for (int r = 0; r < 4; ++r) {
      float mx = fmaxf(fmaxf(sc4[mt][0][r], sc4[mt][1][r]),
                       fmaxf(sc4[mt][2][r], sc4[mt][3][r]));
#pragma unroll
      for (int off = 1; off < 16; off <<= 1) mx = fmaxf(mx, __shfl_xor(mx, off, 64));
      float e0 = __expf(sc4[mt][0][r] - mx);
      float e1 = __expf(sc4[mt][1][r] - mx);
      float e2 = __expf(sc4[mt][2][r] - mx);
      float e3 = __expf(sc4[mt][3][r] - mx);
      float sm = (e0 + e1) + (e2 + e3);
#pragma unroll
      for (int off = 1; off < 16; off <<= 1) sm += __shfl_xor(sm, off, 64);
      float inv = 1.0f / sm;
      int row = mt * 16 + quad * 4 + r;
      Ps[row * 68 +  0 + cl] = (__bf16)(e0 * inv);
      Ps[row * 68 + 16 + cl] = (__bf16)(e1 * inv);
      Ps[row * 68 + 32 + cl] = (__bf16)(e2 * inv);
      Ps[row * 68 + 48 + cl] = (__bf16)(e3 * inv);
    }
  }

  // ---- phase 3: O = P V ----
  f32x4 oacc[4][2];
  {
    bf16x8 bv[2][2];
#pragma unroll
    for (int nt = 0; nt < 2; ++nt)
#pragma unroll
      for (int kt = 0; kt < 2; ++kt)
        bv[nt][kt] = *(const bf16x8*)&Vts[(nt * 16 + cl) * 66 + kt * 32 + quad * 8];
    __builtin_amdgcn_s_setprio(1);
#pragma unroll
    for (int mt = 0; mt < 4; ++mt) {
      bf16x8 ap0 = *(const bf16x8*)&Ps[(mt * 16 + cl) * 68 + quad * 8];
      bf16x8 ap1 = *(const bf16x8*)&Ps[(mt * 16 + cl) * 68 + 32 + quad * 8];
#pragma unroll
      for (int nt = 0; nt < 2; ++nt) {
        f32x4 z = {0.f, 0.f, 0.f, 0.f};
        z = __builtin_amdgcn_mfma_f32_16x16x32_bf16(ap0, bv[nt][0], z, 0, 0, 0);
        z = __builtin_amdgcn_mfma_f32_16x16x32_bf16(ap1, bv[nt][1], z, 0, 0, 0);
        oacc[mt][nt] = z;
      }
    }
    __builtin_amdgcn_s_setprio(0);
  }
#pragma unroll
  for (int mt = 0; mt < 4; ++mt)
#pragma unroll
    for (int nt = 0; nt < 2; ++nt)
#pragma unroll
      for (int r = 0; r < 4; ++r)
        Os[(mt * 16 + quad * 4 + r) * 36 + nt * 16 + cl] = (__bf16)oacc[mt][nt][r];
  __syncthreads();

  // ---- phase 4: proj, wave w owns 32 cols; write o for fl!=2 ----
  const int jw = w * 32;
#pragma unroll
  for (int mt = 0; mt < 4; ++mt) {
#pragma unroll
    for (int nt = 0; nt < 2; ++nt) {
      int col = jw + nt * 16 + cl;
      float pb = projb[col];
      f32x4 acc = {pb, pb, pb, pb};
#pragma unroll
      for (int kt = 0; kt < 4; ++kt) {
        const __bf16* op = scratch + kt * 4352;
        bf16x8 a = *(const bf16x8*)&op[(mt * 16 + cl) * 36 + quad * 8];
        bf16x8 bb = *(const bf16x8*)&projt[(size_t)col * 128 + kt * 32 + quad * 8];
        acc = __builtin_amdgcn_mfma_f32_16x16x32_bf16(a, bb, acc, 0, 0, 0);
      }
#pragma unroll
      for (int r = 0; r < 4; ++r) {
        int row = mt * 16 + quad * 4 + r;
        if (fl[row] != 2)
          out[(size_t)srow[row] * 128 + col] = acc[r];
      }
    }
  }
}

// ---------------- MLP path: R6 structure (BM=64, park-y, 64-col H chunks) ----------------
// LDS: y2s bf16 64x136 (17408B) + hb bf16 64x68 (8704B) + wrs 256B = 26368B
//  => up to 6 blocks/CU (R6-proven best); lb(256,5) VGPR cap ~102 (no spills).
// Phase 0 float4: one row per half-wave, 3 LN chains at 5 shuffle steps each,
// park-y as a full float4 store.
__global__ __launch_bounds__(256, 5) void k_mlp(
    const float* __restrict__ x, const int* __restrict__ iw,
    const int* __restrict__ ia,
    const float* __restrict__ ln1w, const float* __restrict__ ln1b,
    const float* __restrict__ g1,
    const float* __restrict__ ln2w, const float* __restrict__ ln2b,
    const __bf16* __restrict__ w1t, const float* __restrict__ b1,
    const __bf16* __restrict__ w2t, const float* __restrict__ b2,
    const float* __restrict__ g2,
    float* out) {
  __shared__ __align__(16) __bf16 y2s[64 * 136];
  __shared__ __align__(16) __bf16 hb[64 * 68];
  __shared__ int wrs[64];

  const int tid = threadIdx.x;
  const int w = tid >> 6, lane = tid & 63;
  const int quad = lane >> 4, cl = lane & 15;
  const int half = lane >> 5, l32 = lane & 31;

  if (tid < 64) {
    int s = ia[(blockIdx.x << 6) + tid];
    wrs[tid] = iw[s >> 6] * 64 + (s & 63);
  }
  __syncthreads();

  const float4 lw4 = ((const float4*)ln1w)[l32];
  const float4 lb4 = ((const float4*)ln1b)[l32];
  const float4 g14 = ((const float4*)g1)[l32];
  const float4 l2w4 = ((const float4*)ln2w)[l32];
  const float4 l2b4 = ((const float4*)ln2b)[l32];

  // ---- phase 0: gather + LN1(LN1(x)) + residual(o) -> park y (f32 out); LN2 -> y2s ----
  for (int qb = 0; qb < 2; ++qb) {
    float4 xv[4], ov[4];
#pragma unroll
    for (int ii = 0; ii < 4; ++ii) {
      int r = w * 16 + (qb * 4 + ii) * 2 + half;
      size_t wr = (size_t)wrs[r];
      xv[ii] = ((const float4*)(x + wr * 128))[l32];
      ov[ii] = ((const float4*)(out + wr * 128))[l32];
    }
#pragma unroll
    for (int ii = 0; ii < 4; ++ii) {
      int r = w * 16 + (qb * 4 + ii) * 2 + half;
      float4 v = xv[ii];
      float mean = half_sum((v.x + v.y) + (v.z + v.w)) * (1.0f / 128.0f);
      float d0 = v.x - mean, d1 = v.y - mean, d2 = v.z - mean, d3 = v.w - mean;
      float inv = rsqrtf(half_sum((d0 * d0 + d1 * d1) + (d2 * d2 + d3 * d3)) *
                             (1.0f / 128.0f) + 1e-6f);
      float y0 = d0 * inv * lw4.x + lb4.x;
      float y1 = d1 * inv * lw4.y + lb4.y;
      float y2 = d2 * inv * lw4.z + lb4.z;
      float y3 = d3 * inv * lw4.w + lb4.w;
      mean = half_sum((y0 + y1) + (y2 + y3)) * (1.0f / 128.0f);
      d0 = y0 - mean; d1 = y1 - mean; d2 = y2 - mean; d3 = y3 - mean;
      inv = rsqrtf(half_sum((d0 * d0 + d1 * d1) + (d2 * d2 + d3 * d3)) *
                       (1.0f / 128.0f) + 1e-6f);
      float4 yv;
      yv.x = (d0 * inv * lw4.x + lb4.x) + g14.x * ov[ii].x;
      yv.y = (d1 * inv * lw4.y + lb4.y) + g14.y * ov[ii].y;
      yv.z = (d2 * inv * lw4.z + lb4.z) + g14.z * ov[ii].z;
      yv.w = (d3 * inv * lw4.w + lb4.w) + g14.w * ov[ii].w;
      ((float4*)(out + (size_t)wrs[r] * 128))[l32] = yv;  // park y
      mean = half_sum((yv.x + yv.y) + (yv.z + yv.w)) * (1.0f / 128.0f);
      d0 = yv.x - mean; d1 = yv.y - mean; d2 = yv.z - mean; d3 = yv.w - mean;
      inv = rsqrtf(half_sum((d0 * d0 + d1 * d1) + (d2 * d2 + d3 * d3)) *
                       (1.0f / 128.0f) + 1e-6f);
      bf16x4 p4;
      p4[0] = (__bf16)(d0 * inv * l2w4.x + l2b4.x);
      p4[1] = (__bf16)(d1 * inv * l2w4.y + l2b4.y);
      p4[2] = (__bf16)(d2 * inv * l2w4.z + l2b4.z);
      p4[3] = (__bf16)(d3 * inv * l2w4.w + l2b4.w);
      *(bf16x4*)&y2s[r * 136 + l32 * 4] = p4;
    }
  }
  __threadfence_block();
  __syncthreads();

  f32x4 zacc[4][2];
#pragma unroll
  for (int nt = 0; nt < 2; ++nt) {
    float bb = b2[w * 32 + nt * 16 + cl];
#pragma unroll
    for (int mt = 0; mt < 4; ++mt) zacc[mt][nt] = (f32x4){bb, bb, bb, bb};
  }

  for (int ch = 0; ch < 8; ++ch) {
    // ---- GEMM1 chunk: H[:, ch*64 + w*16 .. +16] = gelu(y2 @ W1 + b1) ----
    {
      int col = ch * 64 + w * 16 + cl;
      bf16x8 bfr[4];
#pragma unroll
      for (int kt = 0; kt < 4; ++kt)
        bfr[kt] = *(const bf16x8*)&w1t[(size_t)col * 128 + kt * 32 + quad * 8];
      float bias = b1[col];
      __builtin_amdgcn_s_setprio(1);
#pragma unroll
      for (int mt = 0; mt < 4; ++mt) {
        f32x4 acc = {bias, bias, bias, bias};
#pragma unroll
        for (int kt = 0; kt < 4; ++kt) {
          bf16x8 a = *(const bf16x8*)&y2s[(mt * 16 + cl) * 136 + kt * 32 + quad * 8];
          acc = __builtin_amdgcn_mfma_f32_16x16x32_bf16(a, bfr[kt], acc, 0, 0, 0);
        }
#pragma unroll
        for (int r = 0; r < 4; ++r) {
          float a = acc[r];
          float g = a * 0.5f * (1.0f + erff(a * 0.70710678118654752f));
          hb[(mt * 16 + quad * 4 + r) * 68 + w * 16 + cl] = (__bf16)g;
        }
      }
      __builtin_amdgcn_s_setprio(0);
    }
    __syncthreads();
    // ---- GEMM2 accumulate: Z[:, w*32 .. +32] += H_chunk(64) @ W2[ch*64.., :] ----
#pragma unroll
    for (int nt = 0; nt < 2; ++nt) {
      int col = w * 32 + nt * 16 + cl;
      bf16x8 bfr[2];
#pragma unroll
      for (int kk = 0; kk < 2; ++kk)
        bfr[kk] = *(const bf16x8*)&w2t[(size_t)col * 512 + ch * 64 + kk * 32 + quad * 8];
      __builtin_amdgcn_s_setprio(1);
#pragma unroll
      for (int mt = 0; mt < 4; ++mt)
#pragma unroll
        for (int kk = 0; kk < 2; ++kk) {
          bf16x8 a = *(const bf16x8*)&hb[(mt * 16 + cl) * 68 + kk * 32 + quad * 8];
          zacc[mt][nt] = __builtin_amdgcn_mfma_f32_16x16x32_bf16(a, bfr[kk],
                                                                zacc[mt][nt], 0, 0, 0);
        }
      __builtin_amdgcn_s_setprio(0);
    }
    __syncthreads();
  }

  // ---- epilogue: out = y + g2 * z  (y parked in out) ----
#pragma unroll
  for (int mt = 0; mt < 4; ++mt)
#pragma unroll
    for (int nt = 0; nt < 2; ++nt) {
      int col = w * 32 + nt * 16 + cl;
      float gg = g2[col];
#pragma unroll
      for (int r = 0; r < 4; ++r) {
        int row = mt * 16 + quad * 4 + r;
        size_t a = (size_t)wrs[row] * 128 + col;
        out[a] = out[a] + gg * zacc[mt][nt][r];
      }
    }
}

extern "C" void kernel_launch(void* const* d_in, const int* in_sizes, int n_in,
                              void* d_out, int out_size, void* d_ws, size_t ws_size,
                              hipStream_t stream) {
  const float* x = (const float*)d_in[0];
  const int* iw = (const int*)d_in[1];
  const int* ip = (const int*)d_in[2];
  const int* ia = (const int*)d_in[3];
  const int* ib = (const int*)d_in[4];
  const float* ln1w = (const float*)d_in[7];
  const float* ln1b = (const float*)d_in[8];
  const float* qkvw = (const float*)d_in[9];
  const float* qkvb = (const float*)d_in[10];
  const float* projw = (const float*)d_in[11];
  const float* projb = (const float*)d_in[12];
  const float* g1 = (const float*)d_in[13];
  const float* ln2w = (const float*)d_in[14];
  const float* ln2b = (const float*)d_in[15];
  const float* w1 = (const float*)d_in[16];
  const float* b1 = (const float*)d_in[17];
  const float* w2 = (const float*)d_in[18];
  const float* b2 = (const float*)d_in[19];
  const float* g2 = (const float*)d_in[20];
  float* out = (float*)d_out;

  // ws layout: flags (MW_ B) | qkvt bf16 384x128 | projt bf16 128x128 |
  //            w1t bf16 512x128 | w2t bf16 128x512   (total 640 KB)
  unsigned char* flags = (unsigned char*)d_ws;
  __bf16* qkvt = (__bf16*)((char*)d_ws + MW_);
  __bf16* projt = (__bf16*)((char*)d_ws + MW_ + 384 * 128 * 2);
  __bf16* w1t = (__bf16*)((char*)d_ws + MW_ + 384 * 128 * 2 + 128 * 128 * 2);
  __bf16* w2t = (__bf16*)((char*)d_ws + MW_ + 384 * 128 * 2 + 128 * 128 * 2 + 512 * 128 * 2);

  k_ln_prep_set<<<LNBLK_ + PREPBLK_ + SETBLK_, 256, 0, stream>>>(
      x, ln1w, ln1b, qkvw, projw, w1, w2, qkvt, projt, w1t, w2t, flags, out);
  k_scatter2<<<(A_ + BL_) / 256, 256, 0, stream>>>(flags, ia, ib);
  k_attn<<<M_, 256, 0, stream>>>(iw, ip, flags, ln1w, ln1b, qkvt, qkvb,
                                 projt, projb, out);
  k_mlp<<<A_ / 64, 256, 0, stream>>>(x, iw, ia, ln1w, ln1b, g1, ln2w, ln2b,
                                     w1t, b1, w2t, b2, g2, out);
}